// Round 6
// baseline (183.560 us; speedup 1.0000x reference)
//
#include <hip/hip_runtime.h>
#include <math.h>

typedef _Float16 h2  __attribute__((ext_vector_type(2)));
typedef _Float16 h4  __attribute__((ext_vector_type(4)));
typedef _Float16 h8  __attribute__((ext_vector_type(8)));
typedef float    f4  __attribute__((ext_vector_type(4)));

#define LOG2E 1.44269504f
#define W1P_ELEMS (384*128)
#define W2_ELEMS  (128*128)
#define BM_ROW    68
#define BM_VAR    (64*BM_ROW)        // 4352 floats per mask variant
#define BM_ELEMS  (4*BM_VAR)

static __device__ __forceinline__ h2 pkrtz(float a, float b) {
    auto r = __builtin_amdgcn_cvt_pkrtz(a, b);   // __fp16x2 -> bit-cast
    h2 out;
    __builtin_memcpy(&out, &r, sizeof(out));
    return out;
}
static __device__ __forceinline__ h4 pkrtz4(f4 v) {
    h2 a = pkrtz(v[0], v[1]);
    h2 b = pkrtz(v[2], v[3]);
    h4 r; r[0] = a[0]; r[1] = a[1]; r[2] = b[0]; r[3] = b[1];
    return r;
}

// Prep: permute w1/b1 to [kind][head][e] row order (Q rows pre-scaled by
// 0.25*log2e), convert w2 to fp16, build 4 bias+mask variants (f32, stride 68).
__global__ void prep(const float* __restrict__ w1, const float* __restrict__ b1,
                     const float* __restrict__ w2, const float* __restrict__ rb,
                     _Float16* __restrict__ w1p, _Float16* __restrict__ w2h,
                     float* __restrict__ bmG, float* __restrict__ b1p)
{
    int i = blockIdx.x * 256 + threadIdx.x;      // 0..49151
    if (i < W1P_ELEMS) {
        int jp = i >> 7, col = i & 127;
        int kind = jp >> 7, rem = jp & 127, h = rem >> 4, e = rem & 15;
        int js = (e*8 + h)*3 + kind;             // original w1 row
        float s = (kind == 0) ? 0.25f * LOG2E : 1.0f;
        w1p[i] = (_Float16)(w1[js*128 + col] * s);
    }
    if (i < W2_ELEMS) w2h[i] = (_Float16)w2[i];
    if (i < BM_ELEMS) {
        int v = i / BM_VAR, rem = i - v*BM_VAR;
        int ii = rem / BM_ROW, jj = rem - ii*BM_ROW;   // ii=query, jj=key
        float val = 0.f;
        if (jj < 64) {
            int hi = ii >> 3, wi = ii & 7, hj = jj >> 3, wj = jj & 7;
            val = rb[(hi - hj + 7)*15 + (wi - wj + 7)] * LOG2E;
            if ((v & 2) && ((ii ^ jj) & 32)) val = -INFINITY;  // row mask (Hw==7)
            if ((v & 1) && ((ii ^ jj) & 4))  val = -INFINITY;  // col mask (Ww==7)
        }
        bmG[i] = val;
    }
    if (i < 384) {
        int kind = i >> 7, rem = i & 127, h = rem >> 4, e = rem & 15;
        int js = (e*8 + h)*3 + kind;
        float s = (kind == 0) ? 0.25f * LOG2E : 1.0f;
        b1p[i] = b1[js] * s;
    }
}

// One block per (batch, window). 512 threads = 8 waves; wave w owns head w.
// Q/K stay in registers between projection and attention (fragment layouts
// coincide); only V (wave-private) and O (cross-wave) round-trip LDS.
// LDS 52224 B -> 3 blocks/CU = 24 waves/CU.
__global__ __launch_bounds__(512, 6)
void swin_fused(const float* __restrict__ x,
                const float* __restrict__ b1p,
                const float* __restrict__ b2,
                const _Float16* __restrict__ w1p,
                const _Float16* __restrict__ w2h,
                const float* __restrict__ bmG,
                float* __restrict__ out)
{
    __shared__ __align__(16) _Float16 xh[64*136];   // x staging; later aliased as O
    __shared__ __align__(16) _Float16 Vt[8*16*68];  // [head][e][t]; wave-private slices
    __shared__ __align__(16) float    bmf[64*68];   // [query i][key j] bias*log2e | -inf

    const int tid  = threadIdx.x;
    const int lane = tid & 63;
    const int wv   = tid >> 6;       // wave id 0..7 == head id
    const int quad = lane >> 4;      // 0..3
    const int l16  = lane & 15;

    const int blk = blockIdx.x;
    const int b   = blk >> 6;
    const int Hw  = (blk >> 3) & 7;
    const int Ww  = blk & 7;

    // ---- Phase 0a: gather shifted x rows -> fp16 LDS -------------------------
    {
        const int r0 = tid >> 5;        // 0..15
        const int c4 = tid & 31;        // float4 column
        for (int it = 0; it < 4; ++it) {
            int t  = r0 + it*16;                      // token 0..63
            int gi = (Hw*8 + (t >> 3) + 4) & 63;      // shifted source row
            int gj = (Ww*8 + (t & 7) + 4) & 63;
            f4 v = *(const f4*)(x + ((size_t)b*4096 + gi*64 + gj)*128 + c4*4);
            *(h4*)(&xh[t*136 + c4*4]) = pkrtz4(v);
        }
    }
    // ---- Phase 0b: copy this block's bias+mask variant to LDS ----------------
    {
        const float* src = bmG + ((Hw == 7 ? 2 : 0) + (Ww == 7 ? 1 : 0)) * BM_VAR;
        for (int c = tid; c < BM_VAR/4; c += 512)
            *(f4*)(&bmf[c*4]) = *(const f4*)(src + c*4);
    }
    __syncthreads();   // B1: xh + bmf ready

    // ---- Phase 1: per-head QKV projection, acc stays in registers ------------
    // Tiles: cc=0 -> Q(head wv), 1 -> K, 2 -> V  (rows cc*128 + wv*16 + l16 of w1p)
    f4 acc[3][4];
    for (int cc = 0; cc < 3; ++cc)
        for (int tt = 0; tt < 4; ++tt)
            acc[cc][tt] = (f4){0.f, 0.f, 0.f, 0.f};

    for (int kb = 0; kb < 4; ++kb) {
        h8 bfx[4];
        for (int tt = 0; tt < 4; ++tt)
            bfx[tt] = *(const h8*)(&xh[(tt*16 + l16)*136 + kb*32 + quad*8]);
        for (int cc = 0; cc < 3; ++cc) {
            h8 afw = *(const h8*)(w1p + (size_t)(cc*128 + wv*16 + l16)*128 + kb*32 + quad*8);
            for (int tt = 0; tt < 4; ++tt)
                acc[cc][tt] = __builtin_amdgcn_mfma_f32_16x16x32_f16(afw, bfx[tt], acc[cc][tt], 0, 0, 0);
        }
    }

    // Per-fragment biases (channel = base + quad*4 + r)
    f4 bQ = *(const f4*)(b1p +   0 + wv*16 + quad*4);
    f4 bK = *(const f4*)(b1p + 128 + wv*16 + quad*4);
    f4 bV = *(const f4*)(b1p + 256 + wv*16 + quad*4);

    // V -> LDS [e][t] (wave-private slice; same-wave write->read, no barrier)
    for (int tt = 0; tt < 4; ++tt) {
        f4 v = acc[2][tt] + bV;
        for (int r = 0; r < 4; ++r)
            Vt[wv*1088 + (quad*4 + r)*68 + tt*16 + l16] = (_Float16)v[r];
    }

    // K/Q fragments: D-layout(acc) == A/B-layout for the 16x16x16 S-GEMM.
    h4 ak[4], bq[4];
    for (int mt = 0; mt < 4; ++mt) ak[mt] = pkrtz4(acc[1][mt] + bK);
    for (int nt = 0; nt < 4; ++nt) bq[nt] = pkrtz4(acc[0][nt] + bQ);

    // V^T fragments: m=e (l16), k=token (quad) — needs the LDS transpose.
    h4 av[4];
    for (int kt = 0; kt < 4; ++kt)
        av[kt] = *(const h4*)(&Vt[wv*1088 + l16*68 + kt*16 + quad*4]);

    // ---- Phase 2: attention (head wv), all operands in registers -------------
    h4 Ofrag[4];
    for (int nt = 0; nt < 4; ++nt) {
        // S^T tiles: D[key j][query i]; bias+mask via C operand (f32, no cvt)
        f4 T[4];
        for (int mt = 0; mt < 4; ++mt) {
            f4 cinit = *(const f4*)(&bmf[(nt*16 + l16)*68 + mt*16 + quad*4]);
            T[mt] = __builtin_amdgcn_mfma_f32_16x16x16f16(ak[mt], bq[nt], cinit, 0, 0, 0);
        }
        // softmax over keys, log2 domain, no max-subtraction (|logits| ~ 1;
        // masked = -inf -> exp2 = 0 exactly; softmax is shift-invariant)
        float s = 0.f;
        h4 P[4];
        for (int mt = 0; mt < 4; ++mt) {
            f4 p;
            for (int r = 0; r < 4; ++r) { p[r] = exp2f(T[mt][r]); s += p[r]; }
            P[mt] = pkrtz4(p);
        }
        s += __shfl_xor(s, 16, 64);
        s += __shfl_xor(s, 32, 64);
        float rcp = 1.0f / s;

        // O^T tile: m=e, n=query, k=key; P's C-layout == B-layout (same lane)
        f4 o = {0.f, 0.f, 0.f, 0.f};
        for (int kt = 0; kt < 4; ++kt)
            o = __builtin_amdgcn_mfma_f32_16x16x16f16(av[kt], P[kt], o, 0, 0, 0);
        Ofrag[nt] = pkrtz4(o * rcp);
    }

    __syncthreads();   // B2: all waves done reading xh (phase-1 bfx)
    for (int nt = 0; nt < 4; ++nt)
        *(h4*)(&xh[(nt*16 + l16)*136 + wv*16 + quad*4]) = Ofrag[nt];
    __syncthreads();   // B3: O complete

    // ---- Phase 3: output projection (64x128, K=128), 1 N-tile per wave -------
    {
        int o = wv*16 + l16;            // output channel
        f4 acc3[4] = {{0.f,0.f,0.f,0.f},{0.f,0.f,0.f,0.f},{0.f,0.f,0.f,0.f},{0.f,0.f,0.f,0.f}};
        for (int kb = 0; kb < 4; ++kb) {
            h8 bf = *(const h8*)(w2h + (size_t)o*128 + kb*32 + quad*8);
            for (int mt = 0; mt < 4; ++mt) {
                h8 af = *(const h8*)(&xh[(mt*16 + l16)*136 + kb*32 + quad*8]);
                acc3[mt] = __builtin_amdgcn_mfma_f32_16x16x32_f16(af, bf, acc3[mt], 0, 0, 0);
            }
        }
        float bias = b2[o];
        for (int mt = 0; mt < 4; ++mt) {
            for (int r = 0; r < 4; ++r) {
                int t  = mt*16 + quad*4 + r;
                int gi = Hw*8 + (t >> 3);
                int gj = Ww*8 + (t & 7);
                out[((size_t)b*4096 + gi*64 + gj)*128 + o] = acc3[mt][r] + bias;
            }
        }
    }
}

extern "C" void kernel_launch(void* const* d_in, const int* in_sizes, int n_in,
                              void* d_out, int out_size, void* d_ws, size_t ws_size,
                              hipStream_t stream) {
    (void)in_sizes; (void)n_in; (void)out_size; (void)ws_size;
    const float* x  = (const float*)d_in[0];
    const float* w1 = (const float*)d_in[1];
    const float* b1 = (const float*)d_in[2];
    const float* w2 = (const float*)d_in[3];
    const float* b2 = (const float*)d_in[4];
    const float* rb = (const float*)d_in[5];

    char* ws = (char*)d_ws;
    _Float16* w1p = (_Float16*)ws;                                   // 98304 B
    _Float16* w2h = (_Float16*)(ws + 98304);                         // 32768 B
    float*    bmG = (float*)(ws + 98304 + 32768);                    // 69632 B
    float*    b1p = (float*)(ws + 98304 + 32768 + 69632);            // 1536 B
    float* outp = (float*)d_out;

    prep<<<(W1P_ELEMS + 255)/256, 256, 0, stream>>>(w1, b1, w2, rb, w1p, w2h, bmG, b1p);
    swin_fused<<<32*64, 512, 0, stream>>>(x, b1p, b2, w1p, w2h, bmG, outp);
}